// Round 1
// baseline (169.490 us; speedup 1.0000x reference)
//
#include <hip/hip_runtime.h>
#include <stdint.h>
#include <math.h>

// Problem constants (fixed by the reference)
#define BATCH 8
#define HH 2048
#define WW 2048
#define NTOT (BATCH * HH * WW)          // 33,554,432
#define NWORDS (NTOT / 32)              // 1,048,576 bitmask words
#define CHUNK_WORDS 512                 // 16384 pixels per chunk
#define NCHUNKS (NWORDS / CHUNK_WORDS)  // 2048
#define MAXK 2000000

#define W_T 64
#define H_T 64

// ---------------- Pass 1: 5x5 local-max mask -> bitmask ----------------
__global__ __launch_bounds__(256) void nms_mask(const float* __restrict__ scores,
                                                uint32_t* __restrict__ bitmask) {
    __shared__ float tile[H_T + 4][W_T + 4];   // 68x68 = 18.5 KB
    __shared__ float vmax[H_T][W_T + 4];       // 64x68 = 17.4 KB

    const int w0 = blockIdx.x * W_T;
    const int h0 = blockIdx.y * H_T;
    const int b  = blockIdx.z;
    const float* img = scores + (size_t)b * HH * WW;

    const int tid  = threadIdx.x;
    const int lane = tid & 63;
    const int wv   = tid >> 6;

    // Stage A: load tile + halo (OOB = -inf, matching reduce_window's init)
    for (int r = wv; r < H_T + 4; r += 4) {
        const int h = h0 + r - 2;
        for (int c = lane; c < W_T + 4; c += 64) {
            const int w = w0 + c - 2;
            float v = -INFINITY;
            if ((unsigned)h < (unsigned)HH && (unsigned)w < (unsigned)WW)
                v = img[(size_t)h * WW + w];
            tile[r][c] = v;
        }
    }
    __syncthreads();

    // Stage B: vertical 5-max
    for (int r = wv; r < H_T; r += 4) {
        for (int c = lane; c < W_T + 4; c += 64) {
            float m = fmaxf(fmaxf(tile[r][c], tile[r + 1][c]),
                            fmaxf(tile[r + 2][c], tile[r + 3][c]));
            m = fmaxf(m, tile[r + 4][c]);
            vmax[r][c] = m;
        }
    }
    __syncthreads();

    // Stage C: horizontal 5-max, compare, ballot -> bitmask words
    for (int r = wv; r < H_T; r += 4) {
        float m = fmaxf(fmaxf(vmax[r][lane], vmax[r][lane + 1]),
                        fmaxf(vmax[r][lane + 2], vmax[r][lane + 3]));
        m = fmaxf(m, vmax[r][lane + 4]);
        const float s = tile[r + 2][lane + 2];
        const bool is_max = (s == m) && (s > 0.0f);
        const unsigned long long bal = __ballot(is_max);
        if (lane == 0) {
            const size_t word = (((size_t)(b * HH + h0 + r) * WW) + w0) >> 5;
            bitmask[word]     = (uint32_t)bal;
            bitmask[word + 1] = (uint32_t)(bal >> 32);
        }
    }
}

// ---------------- Pass 2a: per-chunk popcount ----------------
__global__ __launch_bounds__(256) void chunk_count(const uint32_t* __restrict__ bitmask,
                                                   int* __restrict__ counts) {
    const int chunk = blockIdx.x;
    const uint32_t* base = bitmask + (size_t)chunk * CHUNK_WORDS;
    const int tid = threadIdx.x;
    int pc = __popc(base[tid]) + __popc(base[tid + 256]);
    // wave reduce
    for (int d = 32; d >= 1; d >>= 1) pc += __shfl_down(pc, d, 64);
    __shared__ int wsum[4];
    if ((tid & 63) == 0) wsum[tid >> 6] = pc;
    __syncthreads();
    if (tid == 0) counts[chunk] = wsum[0] + wsum[1] + wsum[2] + wsum[3];
}

// ---------------- Pass 2b: exclusive scan of 2048 counts (1 wave) ----------------
__global__ void scan_counts(const int* __restrict__ counts, int* __restrict__ offsets) {
    const int lane = threadIdx.x;  // 0..63, each owns 32 consecutive counts
    int local[32];
    int sum = 0;
#pragma unroll
    for (int i = 0; i < 32; ++i) {
        local[i] = counts[lane * 32 + i];
        sum += local[i];
    }
    int incl = sum;
#pragma unroll
    for (int d = 1; d < 64; d <<= 1) {
        int n = __shfl_up(incl, d, 64);
        if (lane >= d) incl += n;
    }
    int excl = incl - sum;
#pragma unroll
    for (int i = 0; i < 32; ++i) {
        offsets[lane * 32 + i] = excl;
        excl += local[i];
    }
}

// ---------------- Pass 2c: ordered compaction ----------------
__global__ __launch_bounds__(256) void compact(const uint32_t* __restrict__ bitmask,
                                               const int* __restrict__ offsets,
                                               int* __restrict__ out_h,
                                               int* __restrict__ out_w) {
    const int chunk = blockIdx.x;
    const int tid = threadIdx.x;
    const uint32_t* base = bitmask + (size_t)chunk * CHUNK_WORDS;
    uint32_t m0 = base[2 * tid];
    uint32_t m1 = base[2 * tid + 1];
    const int pc0 = __popc(m0);
    const int pc  = pc0 + __popc(m1);

    // block-level exclusive scan of pc (256 threads = 4 waves)
    const int lane = tid & 63, wv = tid >> 6;
    int incl = pc;
#pragma unroll
    for (int d = 1; d < 64; d <<= 1) {
        int n = __shfl_up(incl, d, 64);
        if (lane >= d) incl += n;
    }
    __shared__ int wsums[4];
    if (lane == 63) wsums[wv] = incl;
    __syncthreads();
    int wbase = 0;
    for (int i = 0; i < wv; ++i) wbase += wsums[i];

    int off = offsets[chunk] + wbase + (incl - pc);

    uint32_t idx_base = ((uint32_t)chunk * CHUNK_WORDS + 2 * tid) * 32;
    while (m0) {
        const int bit = __ffs(m0) - 1;
        m0 &= m0 - 1;
        const uint32_t idx = idx_base + bit;
        if (off < MAXK) {
            out_h[off] = (int)((idx >> 11) & 2047);
            out_w[off] = (int)(idx & 2047);
        }
        ++off;
    }
    idx_base += 32;
    while (m1) {
        const int bit = __ffs(m1) - 1;
        m1 &= m1 - 1;
        const uint32_t idx = idx_base + bit;
        if (off < MAXK) {
            out_h[off] = (int)((idx >> 11) & 2047);
            out_w[off] = (int)(idx & 2047);
        }
        ++off;
    }
}

extern "C" void kernel_launch(void* const* d_in, const int* in_sizes, int n_in,
                              void* d_out, int out_size, void* d_ws, size_t ws_size,
                              hipStream_t stream) {
    const float* scores = (const float*)d_in[0];
    int* out = (int*)d_out;

    uint32_t* bitmask = (uint32_t*)d_ws;
    int* counts  = (int*)((char*)d_ws + (size_t)NWORDS * 4);
    int* offsets = counts + NCHUNKS;

    // Fill the whole [2, MAXK] output with -1 (the nonzero fill value).
    hipMemsetAsync(d_out, 0xFF, (size_t)out_size * sizeof(int), stream);

    nms_mask<<<dim3(WW / W_T, HH / H_T, BATCH), 256, 0, stream>>>(scores, bitmask);
    chunk_count<<<NCHUNKS, 256, 0, stream>>>(bitmask, counts);
    scan_counts<<<1, 64, 0, stream>>>(counts, offsets);
    compact<<<NCHUNKS, 256, 0, stream>>>(bitmask, offsets, out, out + MAXK);
}

// Round 2
// 50.040 us; speedup vs baseline: 3.3871x; 3.3871x over previous
//
#include <hip/hip_runtime.h>
#include <stdint.h>
#include <math.h>

// Problem constants (fixed by the reference)
#define BATCH 8
#define HH 2048
#define WW 2048
#define NTOT (BATCH * HH * WW)       // 33,554,432
#define NWORDS (NTOT / 32)           // 1,048,576 bitmask words (4 MB)
#define R 16                         // output rows per block
#define NSTRIPS (HH / R)             // 128
#define NBLK (NSTRIPS * BATCH)       // 1024 blocks == 1024 flat chunks
#define BLK_WORDS (R * WW / 32)      // 1024 words per chunk
#define MAXK 2000000

// ---------------- Pass 1: 5x5 local-max mask -> byte mask + fused count ----
// Block: 256 threads = 4 waves; wave wv covers columns [wv*512, wv*512+512).
// Thread owns 8 consecutive columns + maintains a 2-column halo on each side
// (redundant loads hit the same cachelines -> no extra HBM traffic, and no
// shuffles / LDS / barriers are needed for the horizontal max).
__global__ __launch_bounds__(256) void nms_mask(const float* __restrict__ scores,
                                                uint8_t* __restrict__ maskbytes,
                                                int* __restrict__ counts) {
    const int strip = blockIdx.x;        // 0..NSTRIPS-1
    const int b     = blockIdx.y;        // 0..BATCH-1
    const int tid   = threadIdx.x;
    const int lane  = tid & 63;
    const int wv    = tid >> 6;
    const int c0    = wv * 512 + lane * 8;   // first owned column
    const int h0    = strip * R;
    const float* img  = scores + (size_t)b * HH * WW;
    const float* colp = img + c0;

    const bool has_l = (c0 != 0);
    const bool has_r = (c0 != WW - 8);

    // win[phase][k], k=0..11 <-> columns c0-2 .. c0+9
    float win[5][12];

    // Row loader: fills win[PH][*] for image row h (OOB row -> -inf).
#define LOAD_ROW(PH, hrow)                                                    \
    do {                                                                      \
        const int h_ = (hrow);                                                \
        if ((unsigned)h_ < (unsigned)HH) {                                    \
            const float* p_ = colp + (size_t)h_ * WW;                         \
            float4 a_ = *(const float4*)(p_);                                 \
            float4 b_ = *(const float4*)(p_ + 4);                             \
            win[PH][2] = a_.x; win[PH][3] = a_.y;                             \
            win[PH][4] = a_.z; win[PH][5] = a_.w;                             \
            win[PH][6] = b_.x; win[PH][7] = b_.y;                             \
            win[PH][8] = b_.z; win[PH][9] = b_.w;                             \
            if (has_l) {                                                      \
                float2 hl_ = *(const float2*)(p_ - 2);                        \
                win[PH][0] = hl_.x; win[PH][1] = hl_.y;                       \
            } else { win[PH][0] = -INFINITY; win[PH][1] = -INFINITY; }        \
            if (has_r) {                                                      \
                float2 hr_ = *(const float2*)(p_ + 8);                        \
                win[PH][10] = hr_.x; win[PH][11] = hr_.y;                     \
            } else { win[PH][10] = -INFINITY; win[PH][11] = -INFINITY; }      \
        } else {                                                              \
            _Pragma("unroll")                                                 \
            for (int k_ = 0; k_ < 12; ++k_) win[PH][k_] = -INFINITY;          \
        }                                                                     \
    } while (0)

    // Prologue: rows h0-2 .. h0+1 into phases 0..3
    LOAD_ROW(0, h0 - 2);
    LOAD_ROW(1, h0 - 1);
    LOAD_ROW(2, h0 + 0);
    LOAD_ROW(3, h0 + 1);

    int pc = 0;
    size_t outbyte = (((size_t)(b * HH + h0) * WW) + c0) >> 3;

#pragma unroll
    for (int i = 0; i < R; ++i) {
        LOAD_ROW((4 + i) % 5, h0 + 2 + i);
        const int CEN = (2 + i) % 5;

        // vertical 5-max per column
        float v[12];
#pragma unroll
        for (int k = 0; k < 12; ++k)
            v[k] = fmaxf(fmaxf(fmaxf(win[0][k], win[1][k]),
                               fmaxf(win[2][k], win[3][k])), win[4][k]);
        // horizontal pair maxes
        float p[11];
#pragma unroll
        for (int k = 0; k < 11; ++k) p[k] = fmaxf(v[k], v[k + 1]);

        uint32_t byte = 0;
#pragma unroll
        for (int j = 0; j < 8; ++j) {
            const float hm = fmaxf(fmaxf(p[j], p[j + 2]), v[j + 4]);
            const float s  = win[CEN][j + 2];
            if ((s == hm) && (s > 0.0f)) byte |= (1u << j);
        }
        maskbytes[outbyte] = (uint8_t)byte;
        outbyte += WW / 8;
        pc += __popc(byte);
    }
#undef LOAD_ROW

    // Fused per-chunk count (block's bits are a contiguous flat range)
#pragma unroll
    for (int d = 32; d >= 1; d >>= 1) pc += __shfl_down(pc, d, 64);
    __shared__ int wsum[4];
    if (lane == 0) wsum[wv] = pc;
    __syncthreads();
    if (tid == 0) counts[b * NSTRIPS + strip] = wsum[0] + wsum[1] + wsum[2] + wsum[3];
}

// ---------------- Pass 2: exclusive scan of 1024 counts (1 wave) -----------
__global__ void scan_counts(const int* __restrict__ counts, int* __restrict__ offsets) {
    const int lane = threadIdx.x;  // 0..63, each owns 16 consecutive counts
    int local[16];
    int sum = 0;
#pragma unroll
    for (int i = 0; i < 16; ++i) {
        local[i] = counts[lane * 16 + i];
        sum += local[i];
    }
    int incl = sum;
#pragma unroll
    for (int d = 1; d < 64; d <<= 1) {
        int n = __shfl_up(incl, d, 64);
        if (lane >= d) incl += n;
    }
    int excl = incl - sum;
#pragma unroll
    for (int i = 0; i < 16; ++i) {
        offsets[lane * 16 + i] = excl;
        excl += local[i];
    }
}

// ---------------- Pass 3: ordered compaction -------------------------------
__global__ __launch_bounds__(256) void compact(const uint32_t* __restrict__ bitmask,
                                               const int* __restrict__ offsets,
                                               int* __restrict__ out_h,
                                               int* __restrict__ out_w) {
    const int chunk = blockIdx.x;
    const int tid = threadIdx.x;
    const uint32_t* base = bitmask + (size_t)chunk * BLK_WORDS;
    uint4 m = ((const uint4*)base)[tid];
    uint32_t words[4] = {m.x, m.y, m.z, m.w};
    int pc = __popc(m.x) + __popc(m.y) + __popc(m.z) + __popc(m.w);

    // block-level exclusive scan of pc (256 threads = 4 waves)
    const int lane = tid & 63, wv = tid >> 6;
    int incl = pc;
#pragma unroll
    for (int d = 1; d < 64; d <<= 1) {
        int n = __shfl_up(incl, d, 64);
        if (lane >= d) incl += n;
    }
    __shared__ int wsums[4];
    if (lane == 63) wsums[wv] = incl;
    __syncthreads();
    int wbase = 0;
    for (int i = 0; i < wv; ++i) wbase += wsums[i];

    int off = offsets[chunk] + wbase + (incl - pc);

    uint32_t idx0 = ((uint32_t)chunk * BLK_WORDS + (uint32_t)tid * 4u) * 32u;
#pragma unroll
    for (int wj = 0; wj < 4; ++wj) {
        uint32_t mm = words[wj];
        const uint32_t ib = idx0 + (uint32_t)wj * 32u;
        while (mm) {
            const int bit = __ffs(mm) - 1;
            mm &= mm - 1;
            const uint32_t idx = ib + bit;
            if (off < MAXK) {
                out_h[off] = (int)((idx >> 11) & 2047);
                out_w[off] = (int)(idx & 2047);
            }
            ++off;
        }
    }
}

extern "C" void kernel_launch(void* const* d_in, const int* in_sizes, int n_in,
                              void* d_out, int out_size, void* d_ws, size_t ws_size,
                              hipStream_t stream) {
    const float* scores = (const float*)d_in[0];
    int* out = (int*)d_out;

    uint32_t* bitmask = (uint32_t*)d_ws;
    int* counts  = (int*)((char*)d_ws + (size_t)NWORDS * 4);
    int* offsets = counts + NBLK;

    // Fill the whole [2, MAXK] output with -1 (the nonzero fill value).
    hipMemsetAsync(d_out, 0xFF, (size_t)out_size * sizeof(int), stream);

    nms_mask<<<dim3(NSTRIPS, BATCH), 256, 0, stream>>>(scores, (uint8_t*)bitmask, counts);
    scan_counts<<<1, 64, 0, stream>>>(counts, offsets);
    compact<<<NBLK, 256, 0, stream>>>(bitmask, offsets, out, out + MAXK);
}

// Round 3
// 46.030 us; speedup vs baseline: 3.6821x; 1.0871x over previous
//
#include <hip/hip_runtime.h>
#include <stdint.h>
#include <math.h>

// Problem constants (fixed by the reference)
#define BATCH 8
#define HH 2048
#define WW 2048
#define NTOT (BATCH * HH * WW)       // 33,554,432
#define NWORDS (NTOT / 32)           // 1,048,576 bitmask words (4 MB)
#define R 16                         // output rows per block
#define NSTRIPS (HH / R)             // 128
#define NBLK (NSTRIPS * BATCH)       // 1024 blocks == 1024 flat chunks
#define BLK_WORDS (R * WW / 32)      // 1024 words per chunk
#define MAXK 2000000

// ---------------- Pass 1: 5x5 local-max mask -> byte mask + fused count ----
// Block: 256 threads = 4 waves; wave wv covers columns [wv*512, wv*512+512).
// Thread owns 8 consecutive columns + maintains a 2-column halo on each side
// (redundant loads hit the same cachelines -> no extra HBM traffic, and no
// shuffles / LDS / barriers are needed for the horizontal max).
__global__ __launch_bounds__(256) void nms_mask(const float* __restrict__ scores,
                                                uint8_t* __restrict__ maskbytes,
                                                int* __restrict__ counts) {
    const int strip = blockIdx.x;        // 0..NSTRIPS-1
    const int b     = blockIdx.y;        // 0..BATCH-1
    const int tid   = threadIdx.x;
    const int lane  = tid & 63;
    const int wv    = tid >> 6;
    const int c0    = wv * 512 + lane * 8;   // first owned column
    const int h0    = strip * R;
    const float* img  = scores + (size_t)b * HH * WW;
    const float* colp = img + c0;

    const bool has_l = (c0 != 0);
    const bool has_r = (c0 != WW - 8);

    // win[phase][k], k=0..11 <-> columns c0-2 .. c0+9
    float win[5][12];

    // Row loader: fills win[PH][*] for image row h (OOB row -> -inf).
#define LOAD_ROW(PH, hrow)                                                    \
    do {                                                                      \
        const int h_ = (hrow);                                                \
        if ((unsigned)h_ < (unsigned)HH) {                                    \
            const float* p_ = colp + (size_t)h_ * WW;                         \
            float4 a_ = *(const float4*)(p_);                                 \
            float4 b_ = *(const float4*)(p_ + 4);                             \
            win[PH][2] = a_.x; win[PH][3] = a_.y;                             \
            win[PH][4] = a_.z; win[PH][5] = a_.w;                             \
            win[PH][6] = b_.x; win[PH][7] = b_.y;                             \
            win[PH][8] = b_.z; win[PH][9] = b_.w;                             \
            if (has_l) {                                                      \
                float2 hl_ = *(const float2*)(p_ - 2);                        \
                win[PH][0] = hl_.x; win[PH][1] = hl_.y;                       \
            } else { win[PH][0] = -INFINITY; win[PH][1] = -INFINITY; }        \
            if (has_r) {                                                      \
                float2 hr_ = *(const float2*)(p_ + 8);                        \
                win[PH][10] = hr_.x; win[PH][11] = hr_.y;                     \
            } else { win[PH][10] = -INFINITY; win[PH][11] = -INFINITY; }      \
        } else {                                                              \
            _Pragma("unroll")                                                 \
            for (int k_ = 0; k_ < 12; ++k_) win[PH][k_] = -INFINITY;          \
        }                                                                     \
    } while (0)

    // Prologue: rows h0-2 .. h0+1 into phases 0..3
    LOAD_ROW(0, h0 - 2);
    LOAD_ROW(1, h0 - 1);
    LOAD_ROW(2, h0 + 0);
    LOAD_ROW(3, h0 + 1);

    int pc = 0;
    size_t outbyte = (((size_t)(b * HH + h0) * WW) + c0) >> 3;

#pragma unroll
    for (int i = 0; i < R; ++i) {
        LOAD_ROW((4 + i) % 5, h0 + 2 + i);
        const int CEN = (2 + i) % 5;

        // vertical 5-max per column
        float v[12];
#pragma unroll
        for (int k = 0; k < 12; ++k)
            v[k] = fmaxf(fmaxf(fmaxf(win[0][k], win[1][k]),
                               fmaxf(win[2][k], win[3][k])), win[4][k]);
        // horizontal pair maxes
        float p[11];
#pragma unroll
        for (int k = 0; k < 11; ++k) p[k] = fmaxf(v[k], v[k + 1]);

        uint32_t byte = 0;
#pragma unroll
        for (int j = 0; j < 8; ++j) {
            const float hm = fmaxf(fmaxf(p[j], p[j + 2]), v[j + 4]);
            const float s  = win[CEN][j + 2];
            if ((s == hm) && (s > 0.0f)) byte |= (1u << j);
        }
        maskbytes[outbyte] = (uint8_t)byte;
        outbyte += WW / 8;
        pc += __popc(byte);
    }
#undef LOAD_ROW

    // Fused per-chunk count (block's bits are a contiguous flat range)
#pragma unroll
    for (int d = 32; d >= 1; d >>= 1) pc += __shfl_down(pc, d, 64);
    __shared__ int wsum[4];
    if (lane == 0) wsum[wv] = pc;
    __syncthreads();
    if (tid == 0) counts[b * NSTRIPS + strip] = wsum[0] + wsum[1] + wsum[2] + wsum[3];
}

// ---------------- Pass 2: exclusive scan of 1024 counts (1 wave) -----------
// Also writes the grand total to offsets[NBLK].
__global__ void scan_counts(const int* __restrict__ counts, int* __restrict__ offsets) {
    const int lane = threadIdx.x;  // 0..63, each owns 16 consecutive counts
    int local[16];
    int sum = 0;
#pragma unroll
    for (int i = 0; i < 16; ++i) {
        local[i] = counts[lane * 16 + i];
        sum += local[i];
    }
    int incl = sum;
#pragma unroll
    for (int d = 1; d < 64; d <<= 1) {
        int n = __shfl_up(incl, d, 64);
        if (lane >= d) incl += n;
    }
    int excl = incl - sum;
#pragma unroll
    for (int i = 0; i < 16; ++i) {
        offsets[lane * 16 + i] = excl;
        excl += local[i];
    }
    if (lane == 63) offsets[NBLK] = incl;  // grand total
}

// ---------------- Pass 3: fill only the tail [total, MAXK) with -1 ---------
// Each thread owns 4 consecutive ints (int4-aligned) in BOTH planes.
__global__ __launch_bounds__(256) void tail_fill(const int* __restrict__ total_p,
                                                 int* __restrict__ out_h,
                                                 int* __restrict__ out_w) {
    int total = *total_p;
    if (total < 0) total = 0;
    if (total > MAXK) total = MAXK;

    const int base = (blockIdx.x * 256 + threadIdx.x) * 4;
    if (base >= MAXK) return;
    if (base + 4 <= total) return;  // fully covered by compact's writes

    if (base >= total) {
        const int4 neg = make_int4(-1, -1, -1, -1);
        *(int4*)(out_h + base) = neg;
        *(int4*)(out_w + base) = neg;
    } else {
        // straddles the boundary: scalar writes for elements >= total
#pragma unroll
        for (int j = 0; j < 4; ++j) {
            const int idx = base + j;
            if (idx >= total) { out_h[idx] = -1; out_w[idx] = -1; }
        }
    }
}

// ---------------- Pass 4: ordered compaction -------------------------------
__global__ __launch_bounds__(256) void compact(const uint32_t* __restrict__ bitmask,
                                               const int* __restrict__ offsets,
                                               int* __restrict__ out_h,
                                               int* __restrict__ out_w) {
    const int chunk = blockIdx.x;
    const int tid = threadIdx.x;
    const uint32_t* base = bitmask + (size_t)chunk * BLK_WORDS;
    uint4 m = ((const uint4*)base)[tid];
    uint32_t words[4] = {m.x, m.y, m.z, m.w};
    int pc = __popc(m.x) + __popc(m.y) + __popc(m.z) + __popc(m.w);

    // block-level exclusive scan of pc (256 threads = 4 waves)
    const int lane = tid & 63, wv = tid >> 6;
    int incl = pc;
#pragma unroll
    for (int d = 1; d < 64; d <<= 1) {
        int n = __shfl_up(incl, d, 64);
        if (lane >= d) incl += n;
    }
    __shared__ int wsums[4];
    if (lane == 63) wsums[wv] = incl;
    __syncthreads();
    int wbase = 0;
    for (int i = 0; i < wv; ++i) wbase += wsums[i];

    int off = offsets[chunk] + wbase + (incl - pc);

    uint32_t idx0 = ((uint32_t)chunk * BLK_WORDS + (uint32_t)tid * 4u) * 32u;
#pragma unroll
    for (int wj = 0; wj < 4; ++wj) {
        uint32_t mm = words[wj];
        const uint32_t ib = idx0 + (uint32_t)wj * 32u;
        while (mm) {
            const int bit = __ffs(mm) - 1;
            mm &= mm - 1;
            const uint32_t idx = ib + bit;
            if (off < MAXK) {
                out_h[off] = (int)((idx >> 11) & 2047);
                out_w[off] = (int)(idx & 2047);
            }
            ++off;
        }
    }
}

extern "C" void kernel_launch(void* const* d_in, const int* in_sizes, int n_in,
                              void* d_out, int out_size, void* d_ws, size_t ws_size,
                              hipStream_t stream) {
    const float* scores = (const float*)d_in[0];
    int* out = (int*)d_out;

    uint32_t* bitmask = (uint32_t*)d_ws;
    int* counts  = (int*)((char*)d_ws + (size_t)NWORDS * 4);
    int* offsets = counts + NBLK;   // NBLK+1 ints

    nms_mask<<<dim3(NSTRIPS, BATCH), 256, 0, stream>>>(scores, (uint8_t*)bitmask, counts);
    scan_counts<<<1, 64, 0, stream>>>(counts, offsets);
    tail_fill<<<(MAXK / 4 + 255) / 256, 256, 0, stream>>>(offsets + NBLK, out, out + MAXK);
    compact<<<NBLK, 256, 0, stream>>>(bitmask, offsets, out, out + MAXK);
}

// Round 4
// 42.898 us; speedup vs baseline: 3.9510x; 1.0730x over previous
//
#include <hip/hip_runtime.h>
#include <stdint.h>
#include <math.h>

// Problem constants (fixed by the reference)
#define BATCH 8
#define HH 2048
#define WW 2048
#define NTOT (BATCH * HH * WW)       // 33,554,432
#define NWORDS (NTOT / 32)           // 1,048,576 bitmask words (4 MB)
#define R 16                         // output rows per block
#define NSTRIPS (HH / R)             // 128
#define NBLK (NSTRIPS * BATCH)       // 1024 blocks == 1024 flat chunks
#define BLK_WORDS (R * WW / 32)      // 1024 words per chunk
#define MAXK 2000000
#define TAILBLK ((MAXK / 4 + 255) / 256)   // 1954 blocks cover [0, MAXK) in int4 steps

// ---------------- Pass 1: 5x5 local-max mask -> byte mask + fused count ----
// Block: 256 threads = 4 waves; wave wv covers columns [wv*512, wv*512+512).
// Thread owns 8 consecutive columns + maintains a 2-column halo on each side
// (redundant loads hit the same cachelines -> no extra HBM traffic, and no
// shuffles / LDS / barriers are needed for the horizontal max).
__global__ __launch_bounds__(256) void nms_mask(const float* __restrict__ scores,
                                                uint8_t* __restrict__ maskbytes,
                                                int* __restrict__ counts) {
    const int strip = blockIdx.x;        // 0..NSTRIPS-1
    const int b     = blockIdx.y;        // 0..BATCH-1
    const int tid   = threadIdx.x;
    const int lane  = tid & 63;
    const int wv    = tid >> 6;
    const int c0    = wv * 512 + lane * 8;   // first owned column
    const int h0    = strip * R;
    const float* img  = scores + (size_t)b * HH * WW;
    const float* colp = img + c0;

    const bool has_l = (c0 != 0);
    const bool has_r = (c0 != WW - 8);

    // win[phase][k], k=0..11 <-> columns c0-2 .. c0+9
    float win[5][12];

    // Row loader: fills win[PH][*] for image row h (OOB row -> -inf).
#define LOAD_ROW(PH, hrow)                                                    \
    do {                                                                      \
        const int h_ = (hrow);                                                \
        if ((unsigned)h_ < (unsigned)HH) {                                    \
            const float* p_ = colp + (size_t)h_ * WW;                         \
            float4 a_ = *(const float4*)(p_);                                 \
            float4 b_ = *(const float4*)(p_ + 4);                             \
            win[PH][2] = a_.x; win[PH][3] = a_.y;                             \
            win[PH][4] = a_.z; win[PH][5] = a_.w;                             \
            win[PH][6] = b_.x; win[PH][7] = b_.y;                             \
            win[PH][8] = b_.z; win[PH][9] = b_.w;                             \
            if (has_l) {                                                      \
                float2 hl_ = *(const float2*)(p_ - 2);                        \
                win[PH][0] = hl_.x; win[PH][1] = hl_.y;                       \
            } else { win[PH][0] = -INFINITY; win[PH][1] = -INFINITY; }        \
            if (has_r) {                                                      \
                float2 hr_ = *(const float2*)(p_ + 8);                        \
                win[PH][10] = hr_.x; win[PH][11] = hr_.y;                     \
            } else { win[PH][10] = -INFINITY; win[PH][11] = -INFINITY; }      \
        } else {                                                              \
            _Pragma("unroll")                                                 \
            for (int k_ = 0; k_ < 12; ++k_) win[PH][k_] = -INFINITY;          \
        }                                                                     \
    } while (0)

    // Prologue: rows h0-2 .. h0+1 into phases 0..3
    LOAD_ROW(0, h0 - 2);
    LOAD_ROW(1, h0 - 1);
    LOAD_ROW(2, h0 + 0);
    LOAD_ROW(3, h0 + 1);

    int pc = 0;
    size_t outbyte = (((size_t)(b * HH + h0) * WW) + c0) >> 3;

#pragma unroll
    for (int i = 0; i < R; ++i) {
        LOAD_ROW((4 + i) % 5, h0 + 2 + i);
        const int CEN = (2 + i) % 5;

        // vertical 5-max per column
        float v[12];
#pragma unroll
        for (int k = 0; k < 12; ++k)
            v[k] = fmaxf(fmaxf(fmaxf(win[0][k], win[1][k]),
                               fmaxf(win[2][k], win[3][k])), win[4][k]);
        // horizontal pair maxes
        float p[11];
#pragma unroll
        for (int k = 0; k < 11; ++k) p[k] = fmaxf(v[k], v[k + 1]);

        uint32_t byte = 0;
#pragma unroll
        for (int j = 0; j < 8; ++j) {
            const float hm = fmaxf(fmaxf(p[j], p[j + 2]), v[j + 4]);
            const float s  = win[CEN][j + 2];
            if ((s == hm) && (s > 0.0f)) byte |= (1u << j);
        }
        maskbytes[outbyte] = (uint8_t)byte;
        outbyte += WW / 8;
        pc += __popc(byte);
    }
#undef LOAD_ROW

    // Fused per-chunk count (block's bits are a contiguous flat range)
#pragma unroll
    for (int d = 32; d >= 1; d >>= 1) pc += __shfl_down(pc, d, 64);
    __shared__ int wsum[4];
    if (lane == 0) wsum[wv] = pc;
    __syncthreads();
    if (tid == 0) counts[b * NSTRIPS + strip] = wsum[0] + wsum[1] + wsum[2] + wsum[3];
}

// Block-wide sum of a per-thread int (256 threads = 4 waves), result to all.
__device__ __forceinline__ int block_sum(int v, int tid) {
    const int lane = tid & 63, wv = tid >> 6;
#pragma unroll
    for (int d = 32; d >= 1; d >>= 1) v += __shfl_down(v, d, 64);
    __shared__ int ws[4];
    __shared__ int res;
    if (lane == 0) ws[wv] = v;
    __syncthreads();
    if (tid == 0) res = ws[0] + ws[1] + ws[2] + ws[3];
    __syncthreads();
    return res;
}

// ---------------- Pass 2: fused ordered compaction + tail fill -------------
// Blocks [0, NBLK): compact chunk `blockIdx.x`. Each block recomputes its own
// exclusive prefix from the 4 KB counts array (L2-hot, read by every block).
// Blocks [NBLK, NBLK+TAILBLK): fill out[idx >= total] with -1.
__global__ __launch_bounds__(256) void compact_tail(const uint32_t* __restrict__ bitmask,
                                                    const int* __restrict__ counts,
                                                    int* __restrict__ out_h,
                                                    int* __restrict__ out_w) {
    const int tid = threadIdx.x;

    if (blockIdx.x >= NBLK) {
        // ---- tail-fill role ----
        const uint4 c4 = ((const uint4*)counts)[tid];  // counts[4t .. 4t+3]
        int total = block_sum((int)(c4.x + c4.y + c4.z + c4.w), tid);
        if (total < 0) total = 0;
        if (total > MAXK) total = MAXK;

        const int base = ((int)(blockIdx.x - NBLK) * 256 + tid) * 4;
        if (base >= MAXK) return;
        if (base + 4 <= total) return;  // fully covered by compaction writes

        if (base >= total) {
            const int4 neg = make_int4(-1, -1, -1, -1);
            *(int4*)(out_h + base) = neg;
            *(int4*)(out_w + base) = neg;
        } else {
#pragma unroll
            for (int j = 0; j < 4; ++j) {
                const int idx = base + j;
                if (idx >= total) { out_h[idx] = -1; out_w[idx] = -1; }
            }
        }
        return;
    }

    // ---- compaction role ----
    const int chunk = blockIdx.x;

    // Exclusive prefix of counts[0..chunk) computed from the counts array.
    const uint4 c4 = ((const uint4*)counts)[tid];
    const int i0 = tid * 4;
    int contrib = 0;
    contrib += (i0 + 0 < chunk) ? (int)c4.x : 0;
    contrib += (i0 + 1 < chunk) ? (int)c4.y : 0;
    contrib += (i0 + 2 < chunk) ? (int)c4.z : 0;
    contrib += (i0 + 3 < chunk) ? (int)c4.w : 0;
    const int chunk_base = block_sum(contrib, tid);

    const uint32_t* base = bitmask + (size_t)chunk * BLK_WORDS;
    uint4 m = ((const uint4*)base)[tid];
    uint32_t words[4] = {m.x, m.y, m.z, m.w};
    int pc = __popc(m.x) + __popc(m.y) + __popc(m.z) + __popc(m.w);

    // block-level exclusive scan of pc (256 threads = 4 waves)
    const int lane = tid & 63, wv = tid >> 6;
    int incl = pc;
#pragma unroll
    for (int d = 1; d < 64; d <<= 1) {
        int n = __shfl_up(incl, d, 64);
        if (lane >= d) incl += n;
    }
    __shared__ int wsums[4];
    if (lane == 63) wsums[wv] = incl;
    __syncthreads();
    int wbase = 0;
    for (int i = 0; i < wv; ++i) wbase += wsums[i];

    int off = chunk_base + wbase + (incl - pc);

    uint32_t idx0 = ((uint32_t)chunk * BLK_WORDS + (uint32_t)tid * 4u) * 32u;
#pragma unroll
    for (int wj = 0; wj < 4; ++wj) {
        uint32_t mm = words[wj];
        const uint32_t ib = idx0 + (uint32_t)wj * 32u;
        while (mm) {
            const int bit = __ffs(mm) - 1;
            mm &= mm - 1;
            const uint32_t idx = ib + bit;
            if (off < MAXK) {
                out_h[off] = (int)((idx >> 11) & 2047);
                out_w[off] = (int)(idx & 2047);
            }
            ++off;
        }
    }
}

extern "C" void kernel_launch(void* const* d_in, const int* in_sizes, int n_in,
                              void* d_out, int out_size, void* d_ws, size_t ws_size,
                              hipStream_t stream) {
    const float* scores = (const float*)d_in[0];
    int* out = (int*)d_out;

    uint32_t* bitmask = (uint32_t*)d_ws;
    int* counts = (int*)((char*)d_ws + (size_t)NWORDS * 4);  // NBLK ints, 16B-aligned

    nms_mask<<<dim3(NSTRIPS, BATCH), 256, 0, stream>>>(scores, (uint8_t*)bitmask, counts);
    compact_tail<<<NBLK + TAILBLK, 256, 0, stream>>>(bitmask, counts, out, out + MAXK);
}